// Round 1
// 151.467 us; speedup vs baseline: 1.0882x; 1.0882x over previous
//
#include <hip/hip_runtime.h>

#define B_ 8
#define T_ 2048
#define H_ 256
#define PSTR 40                  // P LDS row stride (elems)
#define SCALE2 0.0901684403f     // (1/16) * log2(e)
#define SLOPE2 0.00563552752f    // 2^-8 * log2(e)

typedef __attribute__((ext_vector_type(8))) short bf16x8;
typedef __attribute__((ext_vector_type(4))) float f32x4;

#define MFMA16(a, b, c) __builtin_amdgcn_mfma_f32_16x16x32_bf16((a), (b), (c), 0, 0, 0)

__device__ __forceinline__ ushort f2bf(float f) {
  unsigned u = __float_as_uint(f);
  u += 0x7FFFu + ((u >> 16) & 1u);   // RNE; finite inputs
  return (ushort)(u >> 16);
}

// async 16B/lane global->LDS DMA (contiguous: LDS = uniform base + lane*16)
__device__ __forceinline__ void gl_lds16(const ushort* g, ushort* l) {
  __builtin_amdgcn_global_load_lds(
      (const __attribute__((address_space(1))) unsigned int*)g,
      (__attribute__((address_space(3))) unsigned int*)l, 16, 0, 0);
}

// ---- prologue: blocks [0,4096) RoPE(k)->bf16 blocked ktile; [4096,5120) v transpose ----
// ktile layout: [b][it=t/32][d8=d/8][kv=t%32][8]   (16KB contiguous per (b,it) tile)
// vtile layout: [b][it][q4=(t%32)/8][h][8]
__global__ void prep_kernel(const float* __restrict__ k, const float* __restrict__ v,
                            ushort* __restrict__ kt, ushort* __restrict__ vt) {
  __shared__ ushort tile[64][72];
  const int bid = blockIdx.x;
  const int tid = threadIdx.x;
  if (bid < 4096) {
    int idx = bid * 256 + tid;          // over B*T*64 (j-pairs)
    int jp = idx & 63, bt = idx >> 6;
    int t = bt & (T_ - 1);
    int b = bt >> 11;
    int j = jp * 2;
    float rv0 = (float)t * exp2f((float)j * -0.103810252959f) * 0.15915494309f;
    float rv1 = (float)t * exp2f((float)(j + 1) * -0.103810252959f) * 0.15915494309f;
    float fr0 = rv0 - floorf(rv0), fr1 = rv1 - floorf(rv1);
    float sn0 = __builtin_amdgcn_sinf(fr0), cs0 = __builtin_amdgcn_cosf(fr0);
    float sn1 = __builtin_amdgcn_sinf(fr1), cs1 = __builtin_amdgcn_cosf(fr1);
    size_t base = (size_t)bt * H_ + j;
    float2 a = *(const float2*)(k + base);
    float2 c = *(const float2*)(k + base + 128);
    ushort2 lo, hi;
    lo.x = f2bf(a.x * cs0 - c.x * sn0); lo.y = f2bf(a.y * cs1 - c.y * sn1);
    hi.x = f2bf(c.x * cs0 + a.x * sn0); hi.y = f2bf(c.y * cs1 + a.y * sn1);
    size_t kdst = (((size_t)(b * 64 + (t >> 5)) * 32 + (j >> 3)) * 32 + (t & 31)) * 8 + (j & 7);
    *(ushort2*)(kt + kdst) = lo;
    *(ushort2*)(kt + kdst + 4096) = hi;   // d8 + 16
  } else {
    // V transpose into blocked vtile, 64x64 tiles, XOR-8 swizzle in LDS
    int bid2 = bid - 4096;
    int b = bid2 >> 7, rem = bid2 & 127;
    int h0 = (rem >> 5) * 64, t0 = (rem & 31) * 64;
    int c4 = tid & 15, r0 = tid >> 4;
#pragma unroll
    for (int p = 0; p < 4; ++p) {
      int row = r0 + p * 16;
      const float4 f = *(const float4*)(v + ((size_t)(b * T_ + t0 + row)) * H_ + h0 + c4 * 4);
      ushort4 u;
      u.x = f2bf(f.x); u.y = f2bf(f.y); u.z = f2bf(f.z); u.w = f2bf(f.w);
      *(ushort4*)&tile[row][(c4 * 4) ^ (8 * ((row >> 3) & 7))] = u;
    }
    __syncthreads();
#pragma unroll
    for (int p = 0; p < 2; ++p) {
      int c = tid + p * 256;
      int h = c >> 3, tc = (c & 7) * 8;
      int xo = 8 * (c & 7);
      ushort4 u0, u1;
      u0.x = tile[tc + 0][h ^ xo]; u0.y = tile[tc + 1][h ^ xo];
      u0.z = tile[tc + 2][h ^ xo]; u0.w = tile[tc + 3][h ^ xo];
      u1.x = tile[tc + 4][h ^ xo]; u1.y = tile[tc + 5][h ^ xo];
      u1.z = tile[tc + 6][h ^ xo]; u1.w = tile[tc + 7][h ^ xo];
      int tg = t0 + tc;
      size_t dst = (((size_t)(b * 64 + (tg >> 5)) * 4 + ((tg >> 3) & 3)) * 256 + (h0 + h)) * 8;
      *(ushort4*)(vt + dst) = u0;
      *(ushort4*)(vt + dst + 4) = u1;
    }
  }
}

// ---- Flash attention, q-tile 128 x 8 waves, kv-split x2: 256 blocks (1/CU),
// 2 waves/SIMD. K AND V double-buffered via global_load_lds; counted vmcnt(4)
// wait (full-iteration prefetch distance, never drained in main loop).
// Writes unnormalized O-partial + l-partial; combine kernel finishes.
__global__ __launch_bounds__(512, 2)
void attn_kernel(const float* __restrict__ q, const ushort* __restrict__ kt,
                 const ushort* __restrict__ vt, float* __restrict__ out,
                 float* __restrict__ o1, float* __restrict__ lpart) {
  __shared__ ushort Ksh[2][8192];       // [buf][d8][kv32][8]  32 KB
  __shared__ ushort Vsh[2][8192];       // [buf][q4][h256][8]  32 KB
  __shared__ ushort Psh[8][16 * PSTR];  // per-wave P          10 KB

  const int tid = threadIdx.x;
  const int w = tid >> 6, lane = tid & 63, quad = lane >> 4, l16 = lane & 15;
  const int b = blockIdx.x;             // linear%8==b -> XCD affinity
  const int q0 = blockIdx.y * 128;
  const int sp = blockIdx.z;
  const int kvb = sp * (T_ / 2);        // global kv offset of this split

  // ---- in-register RoPE of this wave's 16 Q rows into A-frags ----
  bf16x8 aq[8];
  {
    const float* qb = q + ((size_t)(b * T_) + q0 + w * 16) * H_;
    const int t = q0 + w * 16 + l16;
    float qv[8][8];
#pragma unroll
    for (int ks = 0; ks < 8; ++ks) {
      float4 x0 = *(const float4*)(qb + (size_t)l16 * H_ + ks * 32 + quad * 8);
      float4 x1 = *(const float4*)(qb + (size_t)l16 * H_ + ks * 32 + quad * 8 + 4);
      qv[ks][0] = x0.x; qv[ks][1] = x0.y; qv[ks][2] = x0.z; qv[ks][3] = x0.w;
      qv[ks][4] = x1.x; qv[ks][5] = x1.y; qv[ks][6] = x1.z; qv[ks][7] = x1.w;
    }
#pragma unroll
    for (int ks = 0; ks < 4; ++ks)
#pragma unroll
      for (int e = 0; e < 8; ++e) {
        int d = ks * 32 + quad * 8 + e;
        float rv = (float)t * exp2f((float)d * -0.103810252959f) * 0.15915494309f;
        float fr = rv - floorf(rv);
        float sn = __builtin_amdgcn_sinf(fr), cs = __builtin_amdgcn_cosf(fr);
        aq[ks][e]     = (short)f2bf(qv[ks][e] * cs - qv[ks + 4][e] * sn);
        aq[ks + 4][e] = (short)f2bf(qv[ks + 4][e] * cs + qv[ks][e] * sn);
      }
  }

  const f32x4 fzero = {0.f, 0.f, 0.f, 0.f};
  f32x4 O[16], lac = fzero;
#pragma unroll
  for (int ht = 0; ht < 16; ++ht) O[ht] = fzero;
  bf16x8 vones;
#pragma unroll
  for (int i = 0; i < 8; ++i) vones[i] = (short)0x3F80;

  const ushort* ktb = kt + (size_t)(b * 64 + sp * 32) * 8192;
  const ushort* vtb = vt + (size_t)(b * 64 + sp * 32) * 8192;
  const int stoff = tid * 8;            // elems: lane*16B over 512 threads

  // preload tiles 0 and 1 (4 DMA instrs per wave per tile)
#pragma unroll
  for (int tt = 0; tt < 2; ++tt) {
    const ushort* kg = ktb + (size_t)tt * 8192;
    const ushort* vg = vtb + (size_t)tt * 8192;
    gl_lds16(kg + stoff, &Ksh[tt][stoff]);
    gl_lds16(kg + stoff + 4096, &Ksh[tt][stoff + 4096]);
    gl_lds16(vg + stoff, &Vsh[tt][stoff]);
    gl_lds16(vg + stoff + 4096, &Vsh[tt][stoff + 4096]);
  }

  const float arb = SLOPE2 * (float)(q0 + w * 16 + quad * 4);

  for (int it = 0; it < 32; ++it) {
    const int p = it & 1;
    // acquire: wait for tile(it)'s 4 DMAs (issued a full iteration ago);
    // tile(it+1)'s 4 stay in flight. Never vmcnt(0) except last iter.
    __builtin_amdgcn_sched_barrier(0);
    if (it == 31) __builtin_amdgcn_s_waitcnt(0x0070);   // vmcnt(0) lgkm(0)
    else          __builtin_amdgcn_s_waitcnt(0x0F74);   // vmcnt(4)
    __builtin_amdgcn_s_barrier();
    __builtin_amdgcn_sched_barrier(0);

    // QK on Ksh[p]
    f32x4 s[2] = {fzero, fzero};
#pragma unroll
    for (int ks = 0; ks < 8; ++ks)
#pragma unroll
      for (int nt = 0; nt < 2; ++nt) {
        bf16x8 kf = *(const bf16x8*)&Ksh[p][((ks * 4 + quad) * 32 + nt * 16 + l16) * 8];
        s[nt] = MFMA16(aq[ks], kf, s[nt]);
      }

    // p = exp2(s*SCALE2 + SLOPE2*(col-row)) -> wave-private Psh
#pragma unroll
    for (int nt = 0; nt < 2; ++nt) {
      float ac = SLOPE2 * (float)(kvb + it * 32 + nt * 16 + l16);
#pragma unroll
      for (int r = 0; r < 4; ++r) {
        float a0 = ac - arb - SLOPE2 * (float)r;
        float pv = __builtin_amdgcn_exp2f(fmaf(s[nt][r], SCALE2, a0));
        Psh[w][(quad * 4 + r) * PSTR + nt * 16 + l16] = f2bf(pv);
      }
    }

    // PV + rowsum via ones-MFMA (lgkmcnt orders the wave-private write->read)
    bf16x8 pf = *(const bf16x8*)&Psh[w][l16 * PSTR + quad * 8];
    lac = MFMA16(pf, vones, lac);
#pragma unroll
    for (int ht = 0; ht < 16; ++ht) {
      bf16x8 vf = *(const bf16x8*)&Vsh[p][(quad * 256 + ht * 16 + l16) * 8];
      O[ht] = MFMA16(pf, vf, O[ht]);
    }

    // release: drain this wave's LDS reads, then barrier -> buf[p] free
    __builtin_amdgcn_sched_barrier(0);
    __builtin_amdgcn_s_waitcnt(0xC07F);   // lgkmcnt(0) only
    __builtin_amdgcn_s_barrier();
    __builtin_amdgcn_sched_barrier(0);

    // prefetch tile(it+2) into the buffer just freed
    if (it < 30) {
      const ushort* kg = ktb + (size_t)(it + 2) * 8192;
      const ushort* vg = vtb + (size_t)(it + 2) * 8192;
      gl_lds16(kg + stoff, &Ksh[p][stoff]);
      gl_lds16(kg + stoff + 4096, &Ksh[p][stoff + 4096]);
      gl_lds16(vg + stoff, &Vsh[p][stoff]);
      gl_lds16(vg + stoff + 4096, &Vsh[p][stoff + 4096]);
    }
  }

  // epilogue: unnormalized O-partial + l-partial
  float* od = (sp == 0) ? out : o1;
  float* ob = od + ((size_t)(b * T_) + q0 + w * 16) * H_;
#pragma unroll
  for (int r = 0; r < 4; ++r) {
    int row = quad * 4 + r;
#pragma unroll
    for (int ht = 0; ht < 16; ++ht)
      ob[(size_t)row * H_ + ht * 16 + l16] = O[ht][r];
  }
  if (l16 == 0) {
#pragma unroll
    for (int r = 0; r < 4; ++r)
      lpart[(size_t)(sp * B_ + b) * T_ + q0 + w * 16 + quad * 4 + r] = lac[r];
  }
}

// ---- combine: out = (O0 + O1) / (l0 + l1) ----
__global__ void combine_kernel(float* __restrict__ out, const float* __restrict__ o1,
                               const float* __restrict__ lpart) {
  int idx = blockIdx.x * 256 + threadIdx.x;   // over B*T*H/4
  int row = idx >> 6;
  float inv = 1.0f / (lpart[row] + lpart[B_ * T_ + row]);
  float4 a = ((const float4*)out)[idx];
  float4 c = ((const float4*)o1)[idx];
  a.x = (a.x + c.x) * inv; a.y = (a.y + c.y) * inv;
  a.z = (a.z + c.z) * inv; a.w = (a.w + c.w) * inv;
  ((float4*)out)[idx] = a;
}

extern "C" void kernel_launch(void* const* d_in, const int* in_sizes, int n_in,
                              void* d_out, int out_size, void* d_ws, size_t ws_size,
                              hipStream_t stream) {
  const float* q = (const float*)d_in[0];
  const float* k = (const float*)d_in[1];
  const float* v = (const float*)d_in[2];
  float* out = (float*)d_out;

  const size_t elems = (size_t)B_ * T_ * H_;
  ushort* kt = (ushort*)d_ws;
  ushort* vt = kt + elems;
  float* o1 = (float*)(vt + elems);
  float* lpart = o1 + elems;            // 2*B*T floats

  prep_kernel<<<dim3(5120), 256, 0, stream>>>(k, v, kt, vt);
  attn_kernel<<<dim3(B_, T_ / 128, 2), 512, 0, stream>>>(q, kt, vt, out, o1, lpart);
  combine_kernel<<<dim3((B_ * T_ * H_ / 4) / 256), 256, 0, stream>>>(out, o1, lpart);
}